// Round 2
// baseline (831.062 us; speedup 1.0000x reference)
//
#include <hip/hip_runtime.h>
#include <hip/hip_bf16.h>
#include <math.h>

#define N_NODES 100000
#define N_EDGES 1600000
#define TOT_E   (N_EDGES + N_NODES)

__device__ __forceinline__ float lrelu(float v){ return v > 0.f ? v : 0.2f * v; }
__device__ __forceinline__ float elu_(float v){ return v > 0.f ? v : expm1f(v); }
__device__ __forceinline__ ushort f2bf(float f){
  unsigned u = __float_as_uint(f);
  u = (u + 0x7FFFu + ((u >> 16) & 1u)) >> 16;   // RNE
  return (ushort)u;
}
__device__ __forceinline__ float bf2f(ushort u){
  return __uint_as_float(((unsigned)u) << 16);
}

// ---------------- CSR build (by dst) ----------------
__global__ __launch_bounds__(256) void k_zero(int* a, int n){
  int i = blockIdx.x * 256 + threadIdx.x;
  if (i < n) a[i] = 0;
}

__global__ __launch_bounds__(256) void k_count(const int* __restrict__ ei, int* __restrict__ cnt){
  int i = blockIdx.x * 256 + threadIdx.x;
  if (i >= TOT_E) return;
  int d = (i < N_EDGES) ? ei[N_EDGES + i] : (i - N_EDGES);
  atomicAdd(&cnt[d], 1);
}

__global__ __launch_bounds__(1024) void k_scan1(const int* __restrict__ cnt, int* __restrict__ off,
                                                int* __restrict__ bs){
  __shared__ int s[1024];
  int t = threadIdx.x;
  int i = blockIdx.x * 1024 + t;
  int v = (i < N_NODES) ? cnt[i] : 0;
  s[t] = v;
  __syncthreads();
  for (int o = 1; o < 1024; o <<= 1){
    int tmp = 0;
    if (t >= o) tmp = s[t - o];
    __syncthreads();
    if (t >= o) s[t] += tmp;
    __syncthreads();
  }
  if (i < N_NODES) off[i] = s[t] - v;
  if (t == 1023) bs[blockIdx.x] = s[1023];
}

__global__ void k_scan2(int* bs, int* off, int nb){
  if (threadIdx.x == 0 && blockIdx.x == 0){
    int base = 0;
    for (int b = 0; b < nb; ++b){ int t = bs[b]; bs[b] = base; base += t; }
    off[N_NODES] = base;
  }
}

__global__ __launch_bounds__(1024) void k_scan3(int* __restrict__ off, int* __restrict__ cur,
                                                const int* __restrict__ bs){
  int i = blockIdx.x * 1024 + threadIdx.x;
  if (i < N_NODES){
    int v = off[i] + bs[blockIdx.x];
    off[i] = v;
    cur[i] = v;
  }
}

__global__ __launch_bounds__(256) void k_fill(const int* __restrict__ ei, int* __restrict__ cur,
                                              int* __restrict__ csr){
  int i = blockIdx.x * 256 + threadIdx.x;
  if (i >= TOT_E) return;
  int s, d;
  if (i < N_EDGES){ s = ei[i]; d = ei[N_EDGES + i]; }
  else            { s = d = i - N_EDGES; }
  int p = atomicAdd(&cur[d], 1);
  csr[p] = s;
}

// ------- layer-1 GEMM fused with alpha1; h stored bf16 -------
// x:[n,128] @ W:[128,128] -> h(bf16); as1/ad1:[n,2] fp32
__global__ __launch_bounds__(256) void k_gemm1(const float* __restrict__ x, const float* __restrict__ W,
                                               const float* __restrict__ a_src, const float* __restrict__ a_dst,
                                               ushort* __restrict__ h, float* __restrict__ as1,
                                               float* __restrict__ ad1, int n){
  const int cg   = threadIdx.x & 7;     // 8 col-groups of 16
  const int slot = threadIdx.x >> 3;    // 32 slots x 4 rows
  const int r0   = blockIdx.x * 128 + slot * 4;
  const int col0 = cg * 16;

  const float* xp[4];
  #pragma unroll
  for (int i = 0; i < 4; ++i){
    int r = r0 + i; if (r > n - 1) r = n - 1;
    xp[i] = x + (size_t)r * 128;
  }

  float acc[4][16] = {};
  const float* wp = W + col0;
  for (int k = 0; k < 128; ++k){
    float4 w0 = *(const float4*)(wp);
    float4 w1 = *(const float4*)(wp + 4);
    float4 w2 = *(const float4*)(wp + 8);
    float4 w3 = *(const float4*)(wp + 12);
    wp += 128;
    #pragma unroll
    for (int i = 0; i < 4; ++i){
      float xv = xp[i][k];
      acc[i][0]  = fmaf(xv, w0.x, acc[i][0]);  acc[i][1]  = fmaf(xv, w0.y, acc[i][1]);
      acc[i][2]  = fmaf(xv, w0.z, acc[i][2]);  acc[i][3]  = fmaf(xv, w0.w, acc[i][3]);
      acc[i][4]  = fmaf(xv, w1.x, acc[i][4]);  acc[i][5]  = fmaf(xv, w1.y, acc[i][5]);
      acc[i][6]  = fmaf(xv, w1.z, acc[i][6]);  acc[i][7]  = fmaf(xv, w1.w, acc[i][7]);
      acc[i][8]  = fmaf(xv, w2.x, acc[i][8]);  acc[i][9]  = fmaf(xv, w2.y, acc[i][9]);
      acc[i][10] = fmaf(xv, w2.z, acc[i][10]); acc[i][11] = fmaf(xv, w2.w, acc[i][11]);
      acc[i][12] = fmaf(xv, w3.x, acc[i][12]); acc[i][13] = fmaf(xv, w3.y, acc[i][13]);
      acc[i][14] = fmaf(xv, w3.z, acc[i][14]); acc[i][15] = fmaf(xv, w3.w, acc[i][15]);
    }
  }

  #pragma unroll
  for (int i = 0; i < 4; ++i){
    int r = r0 + i;
    // alpha partials (fp32, before bf16 truncation)
    float sp = 0.f, dp = 0.f;
    #pragma unroll
    for (int j = 0; j < 16; ++j){
      sp = fmaf(acc[i][j], a_src[col0 + j], sp);
      dp = fmaf(acc[i][j], a_dst[col0 + j], dp);
    }
    float s0 = (col0 < 64) ? sp : 0.f, s1 = (col0 < 64) ? 0.f : sp;
    float d0 = (col0 < 64) ? dp : 0.f, d1 = (col0 < 64) ? 0.f : dp;
    #pragma unroll
    for (int m = 1; m <= 4; m <<= 1){
      s0 += __shfl_xor(s0, m); s1 += __shfl_xor(s1, m);
      d0 += __shfl_xor(d0, m); d1 += __shfl_xor(d1, m);
    }
    if (r < n){
      union { uint4 q[2]; ushort us[16]; } pk;
      #pragma unroll
      for (int j = 0; j < 16; ++j) pk.us[j] = f2bf(acc[i][j]);
      uint4* dst = (uint4*)(h + (size_t)r * 128 + col0);
      dst[0] = pk.q[0]; dst[1] = pk.q[1];
      if (cg == 0){
        as1[2 * r] = s0; as1[2 * r + 1] = s1;
        ad1[2 * r] = d0; ad1[2 * r + 1] = d1;
      }
    }
  }
}

// ------- layer-2 attention vectors: vs[k] = sum_c W2[k,c]*a_src2[c] -------
__global__ void k_prep2(const float* __restrict__ W2, const float* __restrict__ a_src2,
                        const float* __restrict__ a_dst2, float* __restrict__ vs, float* __restrict__ vd){
  int k = threadIdx.x;  // 128 threads
  float s = 0.f, d = 0.f;
  for (int c = 0; c < 64; ++c){
    float w = W2[k * 64 + c];
    s = fmaf(w, a_src2[c], s);
    d = fmaf(w, a_dst2[c], d);
  }
  vs[k] = s; vd[k] = d;
}

// ------- layer-1 softmax-agg + elu + alpha2, one wave per node -------
__global__ __launch_bounds__(256) void k_agg1(const int* __restrict__ off, const int* __restrict__ csr,
                                              const ushort* __restrict__ h, const float* __restrict__ asl,
                                              const float* __restrict__ adl, const float* __restrict__ b,
                                              const float* __restrict__ vs2, const float* __restrict__ vd2,
                                              float* __restrict__ y, float* __restrict__ as2,
                                              float* __restrict__ ad2){
  int node = blockIdx.x * 4 + (threadIdx.x >> 6);
  int lane = threadIdx.x & 63;
  int s0 = off[node], e0 = off[node + 1];
  float ad0 = adl[2 * node], ad1v = adl[2 * node + 1];

  float m0 = -1e30f, m1 = -1e30f;
  for (int base = s0; base < e0; base += 64){
    int k = base + lane;
    if (k < e0){
      int s = csr[k];
      m0 = fmaxf(m0, lrelu(asl[2 * s] + ad0));
      m1 = fmaxf(m1, lrelu(asl[2 * s + 1] + ad1v));
    }
  }
  for (int m = 32; m; m >>= 1){
    m0 = fmaxf(m0, __shfl_xor(m0, m));
    m1 = fmaxf(m1, __shfl_xor(m1, m));
  }

  float a0 = 0.f, a1 = 0.f, d0 = 0.f, d1 = 0.f;
  for (int k = s0; k < e0; ++k){
    int s = csr[k];
    float w0 = __expf(lrelu(asl[2 * s] + ad0) - m0);
    float w1 = __expf(lrelu(asl[2 * s + 1] + ad1v) - m1);
    d0 += w0; d1 += w1;
    a0 = fmaf(w0, bf2f(h[(size_t)s * 128 + lane]), a0);
    a1 = fmaf(w1, bf2f(h[(size_t)s * 128 + 64 + lane]), a1);
  }
  float o0 = elu_(a0 / (d0 + 1e-16f) + b[lane]);
  float o1 = elu_(a1 / (d1 + 1e-16f) + b[64 + lane]);
  y[(size_t)node * 128 + lane]      = o0;
  y[(size_t)node * 128 + 64 + lane] = o1;

  // alpha2 = y . (W2 @ a2) fused here
  float s2 = fmaf(o0, vs2[lane], o1 * vs2[64 + lane]);
  float d2 = fmaf(o0, vd2[lane], o1 * vd2[64 + lane]);
  for (int m = 32; m; m >>= 1){ s2 += __shfl_xor(s2, m); d2 += __shfl_xor(d2, m); }
  if (lane == 0){ as2[node] = s2; ad2[node] = d2; }
}

// ------- layer-2 softmax-agg with fused @W2 epilogue -------
__global__ __launch_bounds__(256) void k_agg2(const int* __restrict__ off, const int* __restrict__ csr,
                                              const float* __restrict__ y, const float* __restrict__ as2,
                                              const float* __restrict__ ad2, const float* __restrict__ W2,
                                              const float* __restrict__ b2, float* __restrict__ out){
  int node = blockIdx.x * 4 + (threadIdx.x >> 6);
  int lane = threadIdx.x & 63;
  int s0 = off[node], e0 = off[node + 1];
  float adv = ad2[node];

  float mm = -1e30f;
  for (int base = s0; base < e0; base += 64){
    int k = base + lane;
    if (k < e0) mm = fmaxf(mm, lrelu(as2[csr[k]] + adv));
  }
  for (int m = 32; m; m >>= 1) mm = fmaxf(mm, __shfl_xor(mm, m));

  float g0 = 0.f, g1 = 0.f, den = 0.f;
  for (int k = s0; k < e0; ++k){
    int s = csr[k];
    float w = __expf(lrelu(as2[s] + adv) - mm);
    den += w;
    g0 = fmaf(w, y[(size_t)s * 128 + lane], g0);
    g1 = fmaf(w, y[(size_t)s * 128 + 64 + lane], g1);
  }

  // out[:,c] = elu( (g @ W2)[c] / den + b2[c] ),  c = lane
  float acc = 0.f;
  #pragma unroll 8
  for (int k = 0; k < 64; ++k){
    float gk = __shfl(g0, k);
    acc = fmaf(gk, W2[k * 64 + lane], acc);
  }
  #pragma unroll 8
  for (int k = 0; k < 64; ++k){
    float gk = __shfl(g1, k);
    acc = fmaf(gk, W2[(64 + k) * 64 + lane], acc);
  }
  out[(size_t)node * 64 + lane] = elu_(acc / (den + 1e-16f) + b2[lane]);
}

// ---------------- host ----------------
extern "C" void kernel_launch(void* const* d_in, const int* in_sizes, int n_in,
                              void* d_out, int out_size, void* d_ws, size_t ws_size,
                              hipStream_t stream){
  const float* x      = (const float*)d_in[0];
  const int*   ei     = (const int*)d_in[1];     // harness delivers integers as int32
  const float* W1     = (const float*)d_in[2];
  const float* a_src1 = (const float*)d_in[3];
  const float* a_dst1 = (const float*)d_in[4];
  const float* b1     = (const float*)d_in[5];
  const float* W2     = (const float*)d_in[6];
  const float* a_src2 = (const float*)d_in[7];
  const float* a_dst2 = (const float*)d_in[8];
  const float* b2     = (const float*)d_in[9];
  float* out = (float*)d_out;

  // workspace (~61 MB): h1 lives in d_out as bf16 (exactly N*128*2 = out bytes)
  char* ws = (char*)d_ws;
  size_t o = 0;
  auto alloc = [&](size_t bytes){ size_t r = o; o = (o + bytes + 255) & ~(size_t)255; return r; };
  int*   tmpN = (int*)(ws + alloc((size_t)N_NODES * 4));           // counts -> cursor
  int*   bs   = (int*)(ws + alloc(512));
  int*   off  = (int*)(ws + alloc((size_t)(N_NODES + 1) * 4));
  int*   csr  = (int*)(ws + alloc((size_t)TOT_E * 4));
  float* y1   = (float*)(ws + alloc((size_t)N_NODES * 128 * 4));
  float* as1  = (float*)(ws + alloc((size_t)N_NODES * 2 * 4));
  float* ad1  = (float*)(ws + alloc((size_t)N_NODES * 2 * 4));
  float* as2  = (float*)(ws + alloc((size_t)N_NODES * 4));
  float* ad2  = (float*)(ws + alloc((size_t)N_NODES * 4));
  float* vs2  = (float*)(ws + alloc(512));
  float* vd2  = (float*)(ws + alloc(512));
  ushort* h1  = (ushort*)d_out;   // bf16 h1 scratch inside d_out; dead before final write
  (void)ws_size; (void)in_sizes; (void)n_in; (void)out_size;

  const int nblk_nodes = (N_NODES + 255) / 256;
  const int nblk_edges = (TOT_E + 255) / 256;
  const int nblk_scan  = (N_NODES + 1023) / 1024;
  const int nblk_wave4 = N_NODES / 4;

  // CSR build
  k_zero <<<nblk_nodes, 256, 0, stream>>>(tmpN, N_NODES);
  k_count<<<nblk_edges, 256, 0, stream>>>(ei, tmpN);
  k_scan1<<<nblk_scan, 1024, 0, stream>>>(tmpN, off, bs);
  k_scan2<<<1, 1, 0, stream>>>(bs, off, nblk_scan);
  k_scan3<<<nblk_scan, 1024, 0, stream>>>(off, tmpN, bs);
  k_fill <<<nblk_edges, 256, 0, stream>>>(ei, tmpN, csr);

  // layer 1 (+ fused alpha1), small prep for layer-2 attention vectors
  k_gemm1<<<(N_NODES + 127) / 128, 256, 0, stream>>>(x, W1, a_src1, a_dst1, h1, as1, ad1, N_NODES);
  k_prep2<<<1, 128, 0, stream>>>(W2, a_src2, a_dst2, vs2, vd2);
  k_agg1 <<<nblk_wave4, 256, 0, stream>>>(off, csr, h1, as1, ad1, b1, vs2, vd2, y1, as2, ad2);

  // layer 2: aggregate y1 then fused @W2 epilogue (linearity of segment_sum)
  k_agg2 <<<nblk_wave4, 256, 0, stream>>>(off, csr, y1, as2, ad2, W2, b2, out);
}

// Round 3
// 677.549 us; speedup vs baseline: 1.2266x; 1.2266x over previous
//
#include <hip/hip_runtime.h>
#include <hip/hip_bf16.h>
#include <math.h>

#define N_NODES 100000
#define N_EDGES 1600000
#define TOT_E   (N_EDGES + N_NODES)

__device__ __forceinline__ float lrelu(float v){ return v > 0.f ? v : 0.2f * v; }
__device__ __forceinline__ float elu_(float v){ return v > 0.f ? v : expm1f(v); }
__device__ __forceinline__ ushort f2bf(float f){
  unsigned u = __float_as_uint(f);
  u = (u + 0x7FFFu + ((u >> 16) & 1u)) >> 16;   // RNE
  return (ushort)u;
}
__device__ __forceinline__ float bf2f(ushort u){
  return __uint_as_float(((unsigned)u) << 16);
}

// ---------------- CSR build (by dst) ----------------
__global__ __launch_bounds__(256) void k_zero(int* a, int n){
  int i = blockIdx.x * 256 + threadIdx.x;
  if (i < n) a[i] = 0;
}

__global__ __launch_bounds__(256) void k_count(const int* __restrict__ ei, int* __restrict__ cnt){
  int i = blockIdx.x * 256 + threadIdx.x;
  if (i >= TOT_E) return;
  int d = (i < N_EDGES) ? ei[N_EDGES + i] : (i - N_EDGES);
  atomicAdd(&cnt[d], 1);
}

__global__ __launch_bounds__(1024) void k_scan1(const int* __restrict__ cnt, int* __restrict__ off,
                                                int* __restrict__ bs){
  __shared__ int s[1024];
  int t = threadIdx.x;
  int i = blockIdx.x * 1024 + t;
  int v = (i < N_NODES) ? cnt[i] : 0;
  s[t] = v;
  __syncthreads();
  for (int o = 1; o < 1024; o <<= 1){
    int tmp = 0;
    if (t >= o) tmp = s[t - o];
    __syncthreads();
    if (t >= o) s[t] += tmp;
    __syncthreads();
  }
  if (i < N_NODES) off[i] = s[t] - v;
  if (t == 1023) bs[blockIdx.x] = s[1023];
}

__global__ void k_scan2(int* bs, int* off, int nb){
  if (threadIdx.x == 0 && blockIdx.x == 0){
    int base = 0;
    for (int b = 0; b < nb; ++b){ int t = bs[b]; bs[b] = base; base += t; }
    off[N_NODES] = base;
  }
}

__global__ __launch_bounds__(1024) void k_scan3(int* __restrict__ off, int* __restrict__ cur,
                                                const int* __restrict__ bs){
  int i = blockIdx.x * 1024 + threadIdx.x;
  if (i < N_NODES){
    int v = off[i] + bs[blockIdx.x];
    off[i] = v;
    cur[i] = v;
  }
}

__global__ __launch_bounds__(256) void k_fill(const int* __restrict__ ei, int* __restrict__ cur,
                                              int* __restrict__ csr){
  int i = blockIdx.x * 256 + threadIdx.x;
  if (i >= TOT_E) return;
  int s, d;
  if (i < N_EDGES){ s = ei[i]; d = ei[N_EDGES + i]; }
  else            { s = d = i - N_EDGES; }
  int p = atomicAdd(&cur[d], 1);
  csr[p] = s;
}

// ------- layer-1 GEMM fused with alpha1; h stored bf16 (in d_out) -------
__global__ __launch_bounds__(256) void k_gemm1(const float* __restrict__ x, const float* __restrict__ W,
                                               const float* __restrict__ a_src, const float* __restrict__ a_dst,
                                               ushort* __restrict__ h, float* __restrict__ as1,
                                               float* __restrict__ ad1, int n){
  const int cg   = threadIdx.x & 7;     // 8 col-groups of 16
  const int slot = threadIdx.x >> 3;    // 32 slots x 4 rows
  const int r0   = blockIdx.x * 128 + slot * 4;
  const int col0 = cg * 16;

  const float* xp[4];
  #pragma unroll
  for (int i = 0; i < 4; ++i){
    int r = r0 + i; if (r > n - 1) r = n - 1;
    xp[i] = x + (size_t)r * 128;
  }

  float acc[4][16] = {};
  const float* wp = W + col0;
  for (int k = 0; k < 128; ++k){
    float4 w0 = *(const float4*)(wp);
    float4 w1 = *(const float4*)(wp + 4);
    float4 w2 = *(const float4*)(wp + 8);
    float4 w3 = *(const float4*)(wp + 12);
    wp += 128;
    #pragma unroll
    for (int i = 0; i < 4; ++i){
      float xv = xp[i][k];
      acc[i][0]  = fmaf(xv, w0.x, acc[i][0]);  acc[i][1]  = fmaf(xv, w0.y, acc[i][1]);
      acc[i][2]  = fmaf(xv, w0.z, acc[i][2]);  acc[i][3]  = fmaf(xv, w0.w, acc[i][3]);
      acc[i][4]  = fmaf(xv, w1.x, acc[i][4]);  acc[i][5]  = fmaf(xv, w1.y, acc[i][5]);
      acc[i][6]  = fmaf(xv, w1.z, acc[i][6]);  acc[i][7]  = fmaf(xv, w1.w, acc[i][7]);
      acc[i][8]  = fmaf(xv, w2.x, acc[i][8]);  acc[i][9]  = fmaf(xv, w2.y, acc[i][9]);
      acc[i][10] = fmaf(xv, w2.z, acc[i][10]); acc[i][11] = fmaf(xv, w2.w, acc[i][11]);
      acc[i][12] = fmaf(xv, w3.x, acc[i][12]); acc[i][13] = fmaf(xv, w3.y, acc[i][13]);
      acc[i][14] = fmaf(xv, w3.z, acc[i][14]); acc[i][15] = fmaf(xv, w3.w, acc[i][15]);
    }
  }

  #pragma unroll
  for (int i = 0; i < 4; ++i){
    int r = r0 + i;
    float sp = 0.f, dp = 0.f;
    #pragma unroll
    for (int j = 0; j < 16; ++j){
      sp = fmaf(acc[i][j], a_src[col0 + j], sp);
      dp = fmaf(acc[i][j], a_dst[col0 + j], dp);
    }
    float s0 = (col0 < 64) ? sp : 0.f, s1 = (col0 < 64) ? 0.f : sp;
    float d0 = (col0 < 64) ? dp : 0.f, d1 = (col0 < 64) ? 0.f : dp;
    #pragma unroll
    for (int m = 1; m <= 4; m <<= 1){
      s0 += __shfl_xor(s0, m); s1 += __shfl_xor(s1, m);
      d0 += __shfl_xor(d0, m); d1 += __shfl_xor(d1, m);
    }
    if (r < n){
      union { uint4 q[2]; ushort us[16]; } pk;
      #pragma unroll
      for (int j = 0; j < 16; ++j) pk.us[j] = f2bf(acc[i][j]);
      uint4* dst = (uint4*)(h + (size_t)r * 128 + col0);
      dst[0] = pk.q[0]; dst[1] = pk.q[1];
      if (cg == 0){
        as1[2 * r] = s0; as1[2 * r + 1] = s1;
        ad1[2 * r] = d0; ad1[2 * r + 1] = d1;
      }
    }
  }
}

// ------- layer-2 attention vectors: vs[k] = sum_c W2[k,c]*a2[c] -------
__global__ void k_prep2(const float* __restrict__ W2, const float* __restrict__ a_src2,
                        const float* __restrict__ a_dst2, float* __restrict__ vs, float* __restrict__ vd){
  int k = threadIdx.x;  // 128 threads
  float s = 0.f, d = 0.f;
  for (int c = 0; c < 64; ++c){
    float w = W2[k * 64 + c];
    s = fmaf(w, a_src2[c], s);
    d = fmaf(w, a_dst2[c], d);
  }
  vs[k] = s; vd[k] = d;
}

// ------- layer-1 agg (no max pass) + elu + fused z=y@W2 + alpha2 -------
// one wave per node; z bf16; y never materialized
__global__ __launch_bounds__(256) void k_agg1(const int* __restrict__ off, const int* __restrict__ csr,
                                              const ushort* __restrict__ h, const float* __restrict__ asl,
                                              const float* __restrict__ adl, const float* __restrict__ b,
                                              const float* __restrict__ vs2, const float* __restrict__ vd2,
                                              const float* __restrict__ W2,
                                              ushort* __restrict__ z, float* __restrict__ as2,
                                              float* __restrict__ ad2){
  int node = blockIdx.x * 4 + (threadIdx.x >> 6);
  int lane = threadIdx.x & 63;
  int s0 = off[node], e0 = off[node + 1];
  float ad0 = adl[2 * node], ad1v = adl[2 * node + 1];

  float a0 = 0.f, a1 = 0.f, d0 = 0.f, d1 = 0.f;
  int k = s0;
  for (; k + 1 < e0; k += 2){
    int sA = csr[k], sB = csr[k + 1];
    float wA0 = __expf(lrelu(asl[2 * sA] + ad0));
    float wA1 = __expf(lrelu(asl[2 * sA + 1] + ad1v));
    float wB0 = __expf(lrelu(asl[2 * sB] + ad0));
    float wB1 = __expf(lrelu(asl[2 * sB + 1] + ad1v));
    float hA0 = bf2f(h[(size_t)sA * 128 + lane]);
    float hA1 = bf2f(h[(size_t)sA * 128 + 64 + lane]);
    float hB0 = bf2f(h[(size_t)sB * 128 + lane]);
    float hB1 = bf2f(h[(size_t)sB * 128 + 64 + lane]);
    d0 += wA0 + wB0; d1 += wA1 + wB1;
    a0 = fmaf(wA0, hA0, a0); a0 = fmaf(wB0, hB0, a0);
    a1 = fmaf(wA1, hA1, a1); a1 = fmaf(wB1, hB1, a1);
  }
  if (k < e0){
    int sA = csr[k];
    float wA0 = __expf(lrelu(asl[2 * sA] + ad0));
    float wA1 = __expf(lrelu(asl[2 * sA + 1] + ad1v));
    d0 += wA0; d1 += wA1;
    a0 = fmaf(wA0, bf2f(h[(size_t)sA * 128 + lane]), a0);
    a1 = fmaf(wA1, bf2f(h[(size_t)sA * 128 + 64 + lane]), a1);
  }

  float o0 = elu_(a0 / (d0 + 1e-16f) + b[lane]);        // y channel lane
  float o1 = elu_(a1 / (d1 + 1e-16f) + b[64 + lane]);   // y channel 64+lane

  // alpha2 = y . (W2 @ a2)
  float s2 = fmaf(o0, vs2[lane], o1 * vs2[64 + lane]);
  float d2 = fmaf(o0, vd2[lane], o1 * vd2[64 + lane]);
  for (int m = 32; m; m >>= 1){ s2 += __shfl_xor(s2, m); d2 += __shfl_xor(d2, m); }
  if (lane == 0){ as2[node] = s2; ad2[node] = d2; }

  // z[node, lane] = sum_k y[k] * W2[k, lane]  (fp32 y from regs, one bf16 round)
  float zacc = 0.f;
  #pragma unroll 8
  for (int kk = 0; kk < 64; ++kk){
    zacc = fmaf(__shfl(o0, kk), W2[kk * 64 + lane], zacc);
  }
  #pragma unroll 8
  for (int kk = 0; kk < 64; ++kk){
    zacc = fmaf(__shfl(o1, kk), W2[(64 + kk) * 64 + lane], zacc);
  }
  z[(size_t)node * 64 + lane] = f2bf(zacc);
}

// ------- layer-2 agg over pre-projected z (no max pass) -------
__global__ __launch_bounds__(256) void k_agg2(const int* __restrict__ off, const int* __restrict__ csr,
                                              const ushort* __restrict__ z, const float* __restrict__ as2,
                                              const float* __restrict__ ad2, const float* __restrict__ b2,
                                              float* __restrict__ out){
  int node = blockIdx.x * 4 + (threadIdx.x >> 6);
  int lane = threadIdx.x & 63;
  int s0 = off[node], e0 = off[node + 1];
  float adv = ad2[node];

  float g = 0.f, den = 0.f;
  int k = s0;
  for (; k + 1 < e0; k += 2){
    int sA = csr[k], sB = csr[k + 1];
    float wA = __expf(lrelu(as2[sA] + adv));
    float wB = __expf(lrelu(as2[sB] + adv));
    float zA = bf2f(z[(size_t)sA * 64 + lane]);
    float zB = bf2f(z[(size_t)sB * 64 + lane]);
    den += wA + wB;
    g = fmaf(wA, zA, g); g = fmaf(wB, zB, g);
  }
  if (k < e0){
    int sA = csr[k];
    float wA = __expf(lrelu(as2[sA] + adv));
    den += wA;
    g = fmaf(wA, bf2f(z[(size_t)sA * 64 + lane]), g);
  }
  out[(size_t)node * 64 + lane] = elu_(g / (den + 1e-16f) + b2[lane]);
}

// ---------------- host ----------------
extern "C" void kernel_launch(void* const* d_in, const int* in_sizes, int n_in,
                              void* d_out, int out_size, void* d_ws, size_t ws_size,
                              hipStream_t stream){
  const float* x      = (const float*)d_in[0];
  const int*   ei     = (const int*)d_in[1];
  const float* W1     = (const float*)d_in[2];
  const float* a_src1 = (const float*)d_in[3];
  const float* a_dst1 = (const float*)d_in[4];
  const float* b1     = (const float*)d_in[5];
  const float* W2     = (const float*)d_in[6];
  const float* a_src2 = (const float*)d_in[7];
  const float* a_dst2 = (const float*)d_in[8];
  const float* b2     = (const float*)d_in[9];
  float* out = (float*)d_out;

  // workspace (~24 MB); h1 (bf16) lives in d_out until k_agg2 overwrites it
  char* ws = (char*)d_ws;
  size_t o = 0;
  auto alloc = [&](size_t bytes){ size_t r = o; o = (o + bytes + 255) & ~(size_t)255; return r; };
  int*    tmpN = (int*)(ws + alloc((size_t)N_NODES * 4));
  int*    bs   = (int*)(ws + alloc(512));
  int*    off  = (int*)(ws + alloc((size_t)(N_NODES + 1) * 4));
  int*    csr  = (int*)(ws + alloc((size_t)TOT_E * 4));
  float*  as1  = (float*)(ws + alloc((size_t)N_NODES * 2 * 4));
  float*  ad1  = (float*)(ws + alloc((size_t)N_NODES * 2 * 4));
  float*  as2  = (float*)(ws + alloc((size_t)N_NODES * 4));
  float*  ad2  = (float*)(ws + alloc((size_t)N_NODES * 4));
  float*  vs2  = (float*)(ws + alloc(512));
  float*  vd2  = (float*)(ws + alloc(512));
  ushort* z    = (ushort*)(ws + alloc((size_t)N_NODES * 64 * 2));
  ushort* h1   = (ushort*)d_out;
  (void)ws_size; (void)in_sizes; (void)n_in; (void)out_size;

  const int nblk_nodes = (N_NODES + 255) / 256;
  const int nblk_edges = (TOT_E + 255) / 256;
  const int nblk_scan  = (N_NODES + 1023) / 1024;
  const int nblk_wave4 = N_NODES / 4;

  // CSR build
  k_zero <<<nblk_nodes, 256, 0, stream>>>(tmpN, N_NODES);
  k_count<<<nblk_edges, 256, 0, stream>>>(ei, tmpN);
  k_scan1<<<nblk_scan, 1024, 0, stream>>>(tmpN, off, bs);
  k_scan2<<<1, 1, 0, stream>>>(bs, off, nblk_scan);
  k_scan3<<<nblk_scan, 1024, 0, stream>>>(off, tmpN, bs);
  k_fill <<<nblk_edges, 256, 0, stream>>>(ei, tmpN, csr);

  // layer 1 (+ fused alpha1); layer-2 attention vectors
  k_gemm1<<<(N_NODES + 127) / 128, 256, 0, stream>>>(x, W1, a_src1, a_dst1, h1, as1, ad1, N_NODES);
  k_prep2<<<1, 128, 0, stream>>>(W2, a_src2, a_dst2, vs2, vd2);

  // layer-1 agg with fused elu + z = y@W2 + alpha2  (y never materialized)
  k_agg1 <<<nblk_wave4, 256, 0, stream>>>(off, csr, h1, as1, ad1, b1, vs2, vd2, W2, z, as2, ad2);

  // layer-2 agg over z, final elu
  k_agg2 <<<nblk_wave4, 256, 0, stream>>>(off, csr, z, as2, ad2, b2, out);
}

// Round 4
// 616.977 us; speedup vs baseline: 1.3470x; 1.0982x over previous
//
#include <hip/hip_runtime.h>
#include <hip/hip_bf16.h>
#include <math.h>

#define N_NODES 100000
#define N_EDGES 1600000
#define TOT_E   (N_EDGES + N_NODES)

__device__ __forceinline__ float lrelu(float v){ return v > 0.f ? v : 0.2f * v; }
__device__ __forceinline__ float elu_(float v){ return v > 0.f ? v : expm1f(v); }
__device__ __forceinline__ ushort f2bf(float f){
  unsigned u = __float_as_uint(f);
  u = (u + 0x7FFFu + ((u >> 16) & 1u)) >> 16;   // RNE
  return (ushort)u;
}
__device__ __forceinline__ float bf2f(ushort u){
  return __uint_as_float(((unsigned)u) << 16);
}

// ---------------- CSR build (by dst) ----------------
__global__ __launch_bounds__(256) void k_zero(int* a, int n){
  int i = blockIdx.x * 256 + threadIdx.x;
  if (i < n) a[i] = 0;
}

__global__ __launch_bounds__(256) void k_count(const int* __restrict__ ei, int* __restrict__ cnt){
  int i = blockIdx.x * 256 + threadIdx.x;
  if (i >= TOT_E) return;
  int d = (i < N_EDGES) ? ei[N_EDGES + i] : (i - N_EDGES);
  atomicAdd(&cnt[d], 1);
}

__global__ __launch_bounds__(1024) void k_scan1(const int* __restrict__ cnt, int* __restrict__ off,
                                                int* __restrict__ bs){
  __shared__ int s[1024];
  int t = threadIdx.x;
  int i = blockIdx.x * 1024 + t;
  int v = (i < N_NODES) ? cnt[i] : 0;
  s[t] = v;
  __syncthreads();
  for (int o = 1; o < 1024; o <<= 1){
    int tmp = 0;
    if (t >= o) tmp = s[t - o];
    __syncthreads();
    if (t >= o) s[t] += tmp;
    __syncthreads();
  }
  if (i < N_NODES) off[i] = s[t] - v;
  if (t == 1023) bs[blockIdx.x] = s[1023];
}

__global__ void k_scan2(int* bs, int* off, int nb){
  if (threadIdx.x == 0 && blockIdx.x == 0){
    int base = 0;
    for (int b = 0; b < nb; ++b){ int t = bs[b]; bs[b] = base; base += t; }
    off[N_NODES] = base;
  }
}

__global__ __launch_bounds__(1024) void k_scan3(int* __restrict__ off, int* __restrict__ cur,
                                                const int* __restrict__ bs){
  int i = blockIdx.x * 1024 + threadIdx.x;
  if (i < N_NODES){
    int v = off[i] + bs[blockIdx.x];
    off[i] = v;
    cur[i] = v;
  }
}

__global__ __launch_bounds__(256) void k_fill(const int* __restrict__ ei, int* __restrict__ cur,
                                              int* __restrict__ csr){
  int i = blockIdx.x * 256 + threadIdx.x;
  if (i >= TOT_E) return;
  int s, d;
  if (i < N_EDGES){ s = ei[i]; d = ei[N_EDGES + i]; }
  else            { s = d = i - N_EDGES; }
  int p = atomicAdd(&cur[d], 1);
  csr[p] = s;
}

// ------- layer-1 GEMM fused with alpha1; h stored bf16 (in d_out) -------
__global__ __launch_bounds__(256) void k_gemm1(const float* __restrict__ x, const float* __restrict__ W,
                                               const float* __restrict__ a_src, const float* __restrict__ a_dst,
                                               ushort* __restrict__ h, float* __restrict__ as1,
                                               float* __restrict__ ad1, int n){
  const int cg   = threadIdx.x & 7;     // 8 col-groups of 16
  const int slot = threadIdx.x >> 3;    // 32 slots x 4 rows
  const int r0   = blockIdx.x * 128 + slot * 4;
  const int col0 = cg * 16;

  const float* xp[4];
  #pragma unroll
  for (int i = 0; i < 4; ++i){
    int r = r0 + i; if (r > n - 1) r = n - 1;
    xp[i] = x + (size_t)r * 128;
  }

  float acc[4][16] = {};
  const float* wp = W + col0;
  for (int k = 0; k < 128; ++k){
    float4 w0 = *(const float4*)(wp);
    float4 w1 = *(const float4*)(wp + 4);
    float4 w2 = *(const float4*)(wp + 8);
    float4 w3 = *(const float4*)(wp + 12);
    wp += 128;
    #pragma unroll
    for (int i = 0; i < 4; ++i){
      float xv = xp[i][k];
      acc[i][0]  = fmaf(xv, w0.x, acc[i][0]);  acc[i][1]  = fmaf(xv, w0.y, acc[i][1]);
      acc[i][2]  = fmaf(xv, w0.z, acc[i][2]);  acc[i][3]  = fmaf(xv, w0.w, acc[i][3]);
      acc[i][4]  = fmaf(xv, w1.x, acc[i][4]);  acc[i][5]  = fmaf(xv, w1.y, acc[i][5]);
      acc[i][6]  = fmaf(xv, w1.z, acc[i][6]);  acc[i][7]  = fmaf(xv, w1.w, acc[i][7]);
      acc[i][8]  = fmaf(xv, w2.x, acc[i][8]);  acc[i][9]  = fmaf(xv, w2.y, acc[i][9]);
      acc[i][10] = fmaf(xv, w2.z, acc[i][10]); acc[i][11] = fmaf(xv, w2.w, acc[i][11]);
      acc[i][12] = fmaf(xv, w3.x, acc[i][12]); acc[i][13] = fmaf(xv, w3.y, acc[i][13]);
      acc[i][14] = fmaf(xv, w3.z, acc[i][14]); acc[i][15] = fmaf(xv, w3.w, acc[i][15]);
    }
  }

  #pragma unroll
  for (int i = 0; i < 4; ++i){
    int r = r0 + i;
    float sp = 0.f, dp = 0.f;
    #pragma unroll
    for (int j = 0; j < 16; ++j){
      sp = fmaf(acc[i][j], a_src[col0 + j], sp);
      dp = fmaf(acc[i][j], a_dst[col0 + j], dp);
    }
    float s0 = (col0 < 64) ? sp : 0.f, s1 = (col0 < 64) ? 0.f : sp;
    float d0 = (col0 < 64) ? dp : 0.f, d1 = (col0 < 64) ? 0.f : dp;
    #pragma unroll
    for (int m = 1; m <= 4; m <<= 1){
      s0 += __shfl_xor(s0, m); s1 += __shfl_xor(s1, m);
      d0 += __shfl_xor(d0, m); d1 += __shfl_xor(d1, m);
    }
    if (r < n){
      union { uint4 q[2]; ushort us[16]; } pk;
      #pragma unroll
      for (int j = 0; j < 16; ++j) pk.us[j] = f2bf(acc[i][j]);
      uint4* dst = (uint4*)(h + (size_t)r * 128 + col0);
      dst[0] = pk.q[0]; dst[1] = pk.q[1];
      if (cg == 0){
        as1[2 * r] = s0; as1[2 * r + 1] = s1;
        ad1[2 * r] = d0; ad1[2 * r + 1] = d1;
      }
    }
  }
}

// ------- layer-2 attention vectors: vs[k] = sum_c W2[k,c]*a2[c] -------
__global__ void k_prep2(const float* __restrict__ W2, const float* __restrict__ a_src2,
                        const float* __restrict__ a_dst2, float* __restrict__ vs, float* __restrict__ vd){
  int k = threadIdx.x;  // 128 threads
  float s = 0.f, d = 0.f;
  for (int c = 0; c < 64; ++c){
    float w = W2[k * 64 + c];
    s = fmaf(w, a_src2[c], s);
    d = fmaf(w, a_dst2[c], d);
  }
  vs[k] = s; vd[k] = d;
}

// ------- layer-1 agg: half-wave edge split, ushort4 h loads, 1 exp/lane -------
// lanes 0-31 take even CSR slots, 32-63 odd; lane handles channels 4*hl..4*hl+3
// (all within one head). Fused: elu, alpha2, z = y@W2 (bf16).
__global__ __launch_bounds__(256) void k_agg1(const int* __restrict__ off, const int* __restrict__ csr,
                                              const ushort* __restrict__ h, const float* __restrict__ asl,
                                              const float* __restrict__ adl, const float* __restrict__ b,
                                              const float* __restrict__ vs2, const float* __restrict__ vd2,
                                              const float* __restrict__ W2,
                                              ushort* __restrict__ z, float* __restrict__ as2,
                                              float* __restrict__ ad2){
  int node = blockIdx.x * 4 + (threadIdx.x >> 6);
  int lane = threadIdx.x & 63;
  int hl   = lane & 31;
  int half = lane >> 5;
  int head = hl >> 4;            // channels 4*hl.. are in head (hl<16 ? 0 : 1)
  int c0   = hl * 4;
  int s0 = off[node], e0 = off[node + 1];
  float adv = adl[2 * node + head];

  float acc0 = 0.f, acc1 = 0.f, acc2 = 0.f, acc3 = 0.f, den = 0.f;
  int k = s0 + half;
  for (; k + 2 < e0; k += 4){          // two edges per half per iter (4 streams/wave)
    int sA = csr[k], sB = csr[k + 2];
    float lA = asl[2u * sA + head] + adv;
    float lB = asl[2u * sB + head] + adv;
    ushort4 hA = *(const ushort4*)(h + ((unsigned)sA << 7) + c0);
    ushort4 hB = *(const ushort4*)(h + ((unsigned)sB << 7) + c0);
    float wA = __expf(lrelu(lA));
    float wB = __expf(lrelu(lB));
    den += wA + wB;
    acc0 = fmaf(wA, bf2f(hA.x), acc0); acc1 = fmaf(wA, bf2f(hA.y), acc1);
    acc2 = fmaf(wA, bf2f(hA.z), acc2); acc3 = fmaf(wA, bf2f(hA.w), acc3);
    acc0 = fmaf(wB, bf2f(hB.x), acc0); acc1 = fmaf(wB, bf2f(hB.y), acc1);
    acc2 = fmaf(wB, bf2f(hB.z), acc2); acc3 = fmaf(wB, bf2f(hB.w), acc3);
  }
  if (k < e0){
    int sA = csr[k];
    float wA = __expf(lrelu(asl[2u * sA + head] + adv));
    ushort4 hA = *(const ushort4*)(h + ((unsigned)sA << 7) + c0);
    den += wA;
    acc0 = fmaf(wA, bf2f(hA.x), acc0); acc1 = fmaf(wA, bf2f(hA.y), acc1);
    acc2 = fmaf(wA, bf2f(hA.z), acc2); acc3 = fmaf(wA, bf2f(hA.w), acc3);
  }

  // combine even/odd halves (lane <-> lane^32, same channels)
  acc0 += __shfl_xor(acc0, 32); acc1 += __shfl_xor(acc1, 32);
  acc2 += __shfl_xor(acc2, 32); acc3 += __shfl_xor(acc3, 32);
  den  += __shfl_xor(den, 32);

  float inv = 1.f / (den + 1e-16f);
  float o0 = elu_(acc0 * inv + b[c0]);
  float o1 = elu_(acc1 * inv + b[c0 + 1]);
  float o2 = elu_(acc2 * inv + b[c0 + 2]);
  float o3 = elu_(acc3 * inv + b[c0 + 3]);

  // alpha2 = y . (W2 @ a2): per-lane partial over 4 channels, reduce over hl
  float s2 = o0 * vs2[c0] + o1 * vs2[c0 + 1] + o2 * vs2[c0 + 2] + o3 * vs2[c0 + 3];
  float d2 = o0 * vd2[c0] + o1 * vd2[c0 + 1] + o2 * vd2[c0 + 2] + o3 * vd2[c0 + 3];
  #pragma unroll
  for (int m = 16; m; m >>= 1){ s2 += __shfl_xor(s2, m); d2 += __shfl_xor(d2, m); }
  if (lane == 0){ as2[node] = s2; ad2[node] = d2; }

  // z[node, lane] = sum_kk y[kk] * W2[kk, lane]; y[4*q+j] lives in lane q as o_j
  float zacc = 0.f;
  #pragma unroll 4
  for (int q = 0; q < 32; ++q){
    float y0 = __shfl(o0, q), y1 = __shfl(o1, q), y2 = __shfl(o2, q), y3 = __shfl(o3, q);
    const float* wr = W2 + (q * 4) * 64 + lane;
    zacc = fmaf(y0, wr[0],   zacc);
    zacc = fmaf(y1, wr[64],  zacc);
    zacc = fmaf(y2, wr[128], zacc);
    zacc = fmaf(y3, wr[192], zacc);
  }
  z[((unsigned)node << 6) + lane] = f2bf(zacc);
}

// ------- layer-2 agg: half-wave edge split, ushort2 z loads -------
__global__ __launch_bounds__(256) void k_agg2(const int* __restrict__ off, const int* __restrict__ csr,
                                              const ushort* __restrict__ z, const float* __restrict__ as2,
                                              const float* __restrict__ ad2, const float* __restrict__ b2,
                                              float* __restrict__ out){
  int node = blockIdx.x * 4 + (threadIdx.x >> 6);
  int lane = threadIdx.x & 63;
  int hl   = lane & 31;
  int half = lane >> 5;
  int c0   = hl * 2;
  int s0 = off[node], e0 = off[node + 1];
  float adv = ad2[node];

  float g0 = 0.f, g1 = 0.f, den = 0.f;
  int k = s0 + half;
  for (; k + 2 < e0; k += 4){
    int sA = csr[k], sB = csr[k + 2];
    float lA = as2[sA] + adv;
    float lB = as2[sB] + adv;
    ushort2 zA = *(const ushort2*)(z + ((unsigned)sA << 6) + c0);
    ushort2 zB = *(const ushort2*)(z + ((unsigned)sB << 6) + c0);
    float wA = __expf(lrelu(lA));
    float wB = __expf(lrelu(lB));
    den += wA + wB;
    g0 = fmaf(wA, bf2f(zA.x), g0); g1 = fmaf(wA, bf2f(zA.y), g1);
    g0 = fmaf(wB, bf2f(zB.x), g0); g1 = fmaf(wB, bf2f(zB.y), g1);
  }
  if (k < e0){
    int sA = csr[k];
    float wA = __expf(lrelu(as2[sA] + adv));
    ushort2 zA = *(const ushort2*)(z + ((unsigned)sA << 6) + c0);
    den += wA;
    g0 = fmaf(wA, bf2f(zA.x), g0); g1 = fmaf(wA, bf2f(zA.y), g1);
  }

  g0  += __shfl_xor(g0, 32);
  g1  += __shfl_xor(g1, 32);
  den += __shfl_xor(den, 32);

  if (half == 0){
    float inv = 1.f / (den + 1e-16f);
    float2 o;
    o.x = elu_(g0 * inv + b2[c0]);
    o.y = elu_(g1 * inv + b2[c0 + 1]);
    *(float2*)(out + ((unsigned)node << 6) + c0) = o;
  }
}

// ---------------- host ----------------
extern "C" void kernel_launch(void* const* d_in, const int* in_sizes, int n_in,
                              void* d_out, int out_size, void* d_ws, size_t ws_size,
                              hipStream_t stream){
  const float* x      = (const float*)d_in[0];
  const int*   ei     = (const int*)d_in[1];
  const float* W1     = (const float*)d_in[2];
  const float* a_src1 = (const float*)d_in[3];
  const float* a_dst1 = (const float*)d_in[4];
  const float* b1     = (const float*)d_in[5];
  const float* W2     = (const float*)d_in[6];
  const float* a_src2 = (const float*)d_in[7];
  const float* a_dst2 = (const float*)d_in[8];
  const float* b2     = (const float*)d_in[9];
  float* out = (float*)d_out;

  // workspace (~24 MB); h1 (bf16) lives in d_out until k_agg2 overwrites it
  char* ws = (char*)d_ws;
  size_t o = 0;
  auto alloc = [&](size_t bytes){ size_t r = o; o = (o + bytes + 255) & ~(size_t)255; return r; };
  int*    tmpN = (int*)(ws + alloc((size_t)N_NODES * 4));
  int*    bs   = (int*)(ws + alloc(512));
  int*    off  = (int*)(ws + alloc((size_t)(N_NODES + 1) * 4));
  int*    csr  = (int*)(ws + alloc((size_t)TOT_E * 4));
  float*  as1  = (float*)(ws + alloc((size_t)N_NODES * 2 * 4));
  float*  ad1  = (float*)(ws + alloc((size_t)N_NODES * 2 * 4));
  float*  as2  = (float*)(ws + alloc((size_t)N_NODES * 4));
  float*  ad2  = (float*)(ws + alloc((size_t)N_NODES * 4));
  float*  vs2  = (float*)(ws + alloc(512));
  float*  vd2  = (float*)(ws + alloc(512));
  ushort* z    = (ushort*)(ws + alloc((size_t)N_NODES * 64 * 2));
  ushort* h1   = (ushort*)d_out;
  (void)ws_size; (void)in_sizes; (void)n_in; (void)out_size;

  const int nblk_nodes = (N_NODES + 255) / 256;
  const int nblk_edges = (TOT_E + 255) / 256;
  const int nblk_scan  = (N_NODES + 1023) / 1024;
  const int nblk_wave4 = N_NODES / 4;

  // CSR build
  k_zero <<<nblk_nodes, 256, 0, stream>>>(tmpN, N_NODES);
  k_count<<<nblk_edges, 256, 0, stream>>>(ei, tmpN);
  k_scan1<<<nblk_scan, 1024, 0, stream>>>(tmpN, off, bs);
  k_scan2<<<1, 1, 0, stream>>>(bs, off, nblk_scan);
  k_scan3<<<nblk_scan, 1024, 0, stream>>>(off, tmpN, bs);
  k_fill <<<nblk_edges, 256, 0, stream>>>(ei, tmpN, csr);

  // layer 1 (+ fused alpha1); layer-2 attention vectors
  k_gemm1<<<(N_NODES + 127) / 128, 256, 0, stream>>>(x, W1, a_src1, a_dst1, h1, as1, ad1, N_NODES);
  k_prep2<<<1, 128, 0, stream>>>(W2, a_src2, a_dst2, vs2, vd2);

  // layer-1 agg with fused elu + z = y@W2 + alpha2  (y never materialized)
  k_agg1 <<<nblk_wave4, 256, 0, stream>>>(off, csr, h1, as1, ad1, b1, vs2, vd2, W2, z, as2, ad2);

  // layer-2 agg over z, final elu
  k_agg2 <<<nblk_wave4, 256, 0, stream>>>(off, csr, z, as2, ad2, b2, out);
}